// Round 1
// baseline (1355.579 us; speedup 1.0000x reference)
//
#include <hip/hip_runtime.h>
#include <math.h>

#define B_ 32
#define N_ 16384
#define K_ 64
#define D_ 256
#define EPS_INV 20.0f                    // 1/0.05 (exact)
#define NEG_CLAMP (-100.0f)
#define LOG_NU (-4.1588830833596715f)    // -log(64)
#define NUM_ITERS_ 20

// ---------------- Phase 1: log_K = max(-C/eps, -100) -> d_out ----------------
// grid (N/256, B), block 256: tx = t&7 (8 k's each), ty = t>>3 (8 n's each)
// d-chunks of 32, LDS layout [row][d] with XOR swizzle on d to kill bank conflicts.
#define P1_TN 256
#define P1_DC 32

__global__ __launch_bounds__(256) void logk_kernel(
    const float* __restrict__ pix, const float* __restrict__ slot,
    float* __restrict__ out)
{
  __shared__ float pl[P1_TN][P1_DC + 4];
  __shared__ float sl[K_][P1_DC + 4];
  const int t  = threadIdx.x;
  const int tx = t & 7;        // k octet
  const int ty = t >> 3;       // n octet (0..31)
  const int b  = blockIdx.y;
  const int n0 = blockIdx.x * P1_TN;
  const float* pg = pix + ((size_t)b * N_ + n0) * D_;
  const float* sg = slot + (size_t)b * K_ * D_;

  float acc[8][8];
  float psq[8], ssq[8];
#pragma unroll
  for (int i = 0; i < 8; ++i) {
    psq[i] = 0.f; ssq[i] = 0.f;
#pragma unroll
    for (int j = 0; j < 8; ++j) acc[i][j] = 0.f;
  }

  for (int d0 = 0; d0 < D_; d0 += P1_DC) {
    __syncthreads();
    // p chunk: 256 n x 32 d = 2048 float4, 8 per thread
#pragma unroll
    for (int r = 0; r < 8; ++r) {
      int u = r * 256 + t;
      int n = u >> 3, dq = u & 7;
      float4 v = *(const float4*)(pg + (size_t)n * D_ + d0 + dq * 4);
      int dsw = (dq * 4) ^ (((n >> 3) & 7) * 4);
      *(float4*)&pl[n][dsw] = v;
    }
    // s chunk: 64 k x 32 d = 512 float4, 2 per thread
#pragma unroll
    for (int r = 0; r < 2; ++r) {
      int u = r * 256 + t;
      int k = u >> 3, dq = u & 7;
      float4 v = *(const float4*)(sg + (size_t)k * D_ + d0 + dq * 4);
      int dsw = (dq * 4) ^ (((k >> 3) & 7) * 4);
      *(float4*)&sl[k][dsw] = v;
    }
    __syncthreads();

    const int pswz = (ty & 7) * 4;   // (n>>3)&7 == ty for all 8 rows of this thread
    const int sswz = (tx & 7) * 4;   // (k>>3)&7 == tx
#pragma unroll
    for (int dd = 0; dd < P1_DC; dd += 4) {
      float4 pv[8], sv[8];
#pragma unroll
      for (int i = 0; i < 8; ++i)
        pv[i] = *(const float4*)&pl[ty * 8 + i][dd ^ pswz];
#pragma unroll
      for (int j = 0; j < 8; ++j)
        sv[j] = *(const float4*)&sl[tx * 8 + j][dd ^ sswz];
#pragma unroll
      for (int i = 0; i < 8; ++i) {
        psq[i] = fmaf(pv[i].x, pv[i].x, psq[i]);
        psq[i] = fmaf(pv[i].y, pv[i].y, psq[i]);
        psq[i] = fmaf(pv[i].z, pv[i].z, psq[i]);
        psq[i] = fmaf(pv[i].w, pv[i].w, psq[i]);
      }
#pragma unroll
      for (int j = 0; j < 8; ++j) {
        ssq[j] = fmaf(sv[j].x, sv[j].x, ssq[j]);
        ssq[j] = fmaf(sv[j].y, sv[j].y, ssq[j]);
        ssq[j] = fmaf(sv[j].z, sv[j].z, ssq[j]);
        ssq[j] = fmaf(sv[j].w, sv[j].w, ssq[j]);
      }
#pragma unroll
      for (int i = 0; i < 8; ++i)
#pragma unroll
        for (int j = 0; j < 8; ++j) {
          acc[i][j] = fmaf(pv[i].x, sv[j].x, acc[i][j]);
          acc[i][j] = fmaf(pv[i].y, sv[j].y, acc[i][j]);
          acc[i][j] = fmaf(pv[i].z, sv[j].z, acc[i][j]);
          acc[i][j] = fmaf(pv[i].w, sv[j].w, acc[i][j]);
        }
    }
  }

  // epilogue: C = psq + ssq - 2*acc ; log_K = max(-C/eps, -100)
#pragma unroll
  for (int i = 0; i < 8; ++i) {
    float* op = out + (((size_t)b * N_ + n0 + ty * 8 + i) * K_) + tx * 8;
    float4 o[2];
#pragma unroll
    for (int j = 0; j < 8; ++j) {
      float C = psq[i] + ssq[j] - 2.f * acc[i][j];
      float lk = fmaxf(-EPS_INV * C, NEG_CLAMP);
      ((float*)o)[j] = lk;
    }
    *(float4*)(op) = o[0];
    *(float4*)(op + 4) = o[1];
  }
}

// ---------------- Sinkhorn iteration ----------------
// Kernel A: row update (exact LSE over k) + per-block column-LSE partials
#define A_ROWS 128
#define A_NBLK (N_ / A_ROWS)   // 128

__global__ __launch_bounds__(256) void sink_row_kernel(
    const float* __restrict__ logk,   // d_out, [B][N][K]
    const float* __restrict__ sw,     // [B][N]
    const float* __restrict__ lv,     // [B][K]
    float* __restrict__ lu,           // [B][N]
    float* __restrict__ pm,           // [B][NBLK][K]
    float* __restrict__ ps)           // [B][NBLK][K]
{
  __shared__ float tile[A_ROWS][K_ + 1];   // stride 65: conflict-free both axes
  __shared__ float lv_s[K_];
  __shared__ float lu_s[A_ROWS];
  __shared__ float wm[4][K_], wsum[4][K_];

  const int t = threadIdx.x;
  const int b = blockIdx.y, blk = blockIdx.x;
  const int n0 = blk * A_ROWS;
  const float* src = logk + ((size_t)b * N_ + n0) * K_;

  // load tile: 128x64 floats = 2048 float4, 8 per thread (coalesced)
#pragma unroll
  for (int r = 0; r < 8; ++r) {
    int u = r * 256 + t;
    int n = u >> 4, kq = u & 15;
    float4 v = *(const float4*)(src + (size_t)n * K_ + kq * 4);
    tile[n][kq * 4 + 0] = v.x; tile[n][kq * 4 + 1] = v.y;
    tile[n][kq * 4 + 2] = v.z; tile[n][kq * 4 + 3] = v.w;
  }
  if (t < K_) lv_s[t] = lv[b * K_ + t];
  __syncthreads();

  // row pass: 2 threads per row, exact two-pass LSE over 64 k's
  {
    const int r = t >> 1, h = t & 1;
    const int kb = 32 * h;
    float m = -INFINITY;
#pragma unroll
    for (int kk = 0; kk < 32; ++kk)
      m = fmaxf(m, tile[r][kb + kk] + lv_s[kb + kk]);
    m = fmaxf(m, __shfl_xor(m, 1));
    float s = 0.f;
#pragma unroll
    for (int kk = 0; kk < 32; ++kk)
      s += __expf(tile[r][kb + kk] + lv_s[kb + kk] - m);
    s += __shfl_xor(s, 1);
    if (h == 0) {
      float lmu = __logf(fmaxf(sw[(size_t)b * N_ + n0 + r], 1e-8f));
      float u_ = lmu - (m + __logf(s));
      lu_s[r] = u_;
      lu[(size_t)b * N_ + n0 + r] = u_;
    }
  }
  __syncthreads();

  // col partials: wave w handles rows [32w,32w+32), lane l = k
  {
    const int w = t >> 6, l = t & 63;
    float m = -INFINITY;
    for (int r = 32 * w; r < 32 * w + 32; ++r)
      m = fmaxf(m, tile[r][l] + lu_s[r]);
    float s = 0.f;
    for (int r = 32 * w; r < 32 * w + 32; ++r)
      s += __expf(tile[r][l] + lu_s[r] - m);
    wm[w][l] = m; wsum[w][l] = s;
  }
  __syncthreads();
  if (t < K_) {
    float m0 = fmaxf(fmaxf(wm[0][t], wm[1][t]), fmaxf(wm[2][t], wm[3][t]));
    float s = wsum[0][t] * __expf(wm[0][t] - m0)
            + wsum[1][t] * __expf(wm[1][t] - m0)
            + wsum[2][t] * __expf(wm[2][t] - m0)
            + wsum[3][t] * __expf(wm[3][t] - m0);
    size_t o = ((size_t)b * A_NBLK + blk) * K_ + t;
    pm[o] = m0; ps[o] = s;
  }
}

// Kernel B: merge NBLK partials per (b,k) -> log_v
__global__ __launch_bounds__(64) void sink_col_kernel(
    const float* __restrict__ pm, const float* __restrict__ ps,
    float* __restrict__ lv)
{
  const int b = blockIdx.x, l = threadIdx.x;
  float m = -INFINITY, s = 0.f;
  for (int i = 0; i < A_NBLK; ++i) {
    size_t o = ((size_t)b * A_NBLK + i) * K_ + l;
    float mi = pm[o], si = ps[o];
    float mn = fmaxf(m, mi);
    s = s * __expf(m - mn) + si * __expf(mi - mn);
    m = mn;
  }
  lv[b * K_ + l] = LOG_NU - (m + __logf(s));
}

// ---------------- Finalize: out = exp(lu + logK + lv), in place ----------------
__global__ __launch_bounds__(256) void finalize_kernel(
    float* __restrict__ out, const float* __restrict__ lu,
    const float* __restrict__ lv)
{
  const size_t idx = (size_t)blockIdx.x * 256 + threadIdx.x; // float4 index
  const size_t e0 = idx * 4;
  const int k0 = (int)(e0 & 63);
  const size_t bn = e0 >> 6;          // b*N + n
  const int b = (int)(bn >> 14);      // N = 2^14
  const float u = lu[bn];
  const float4 v4 = *(const float4*)(lv + b * K_ + k0);
  float4 o = *(float4*)(out + e0);
  o.x = __expf(o.x + u + v4.x);
  o.y = __expf(o.y + u + v4.y);
  o.z = __expf(o.z + u + v4.z);
  o.w = __expf(o.w + u + v4.w);
  *(float4*)(out + e0) = o;
}

__global__ void init_lv_kernel(float* lv)
{
  int i = blockIdx.x * 256 + threadIdx.x;
  if (i < B_ * K_) lv[i] = 0.f;
}

extern "C" void kernel_launch(void* const* d_in, const int* in_sizes, int n_in,
                              void* d_out, int out_size, void* d_ws, size_t ws_size,
                              hipStream_t stream)
{
  const float* pix  = (const float*)d_in[0];
  const float* slot = (const float*)d_in[1];
  const float* sw   = (const float*)d_in[2];
  float* out = (float*)d_out;

  char* ws = (char*)d_ws;
  float* lu = (float*)ws;                                    // B*N   = 2 MB
  float* lv = (float*)(ws + (size_t)B_ * N_ * 4);            // B*K   = 8 KB
  float* pm = (float*)(ws + (size_t)B_ * N_ * 4 + 64 * 1024);// B*NBLK*K = 1 MB
  float* ps = pm + (size_t)B_ * A_NBLK * K_;                 // 1 MB

  hipLaunchKernelGGL(init_lv_kernel, dim3(8), dim3(256), 0, stream, lv);
  hipLaunchKernelGGL(logk_kernel, dim3(N_ / P1_TN, B_), dim3(256), 0, stream,
                     pix, slot, out);
  for (int it = 0; it < NUM_ITERS_; ++it) {
    hipLaunchKernelGGL(sink_row_kernel, dim3(A_NBLK, B_), dim3(256), 0, stream,
                       out, sw, lv, lu, pm, ps);
    hipLaunchKernelGGL(sink_col_kernel, dim3(B_), dim3(64), 0, stream,
                       pm, ps, lv);
  }
  hipLaunchKernelGGL(finalize_kernel,
                     dim3((unsigned)(((size_t)B_ * N_ * K_ / 4) / 256)), dim3(256),
                     0, stream, out, lu, lv);
}

// Round 2
// 846.749 us; speedup vs baseline: 1.6009x; 1.6009x over previous
//
#include <hip/hip_runtime.h>
#include <math.h>

#define B_ 32
#define N_ 16384
#define K_ 64
#define D_ 256
#define EPS_INV 20.0f
#define NEG_CLAMP (-100.0f)
#define LOG_NU (-4.1588830833596715f)    // -log(64)
#define NUM_ITERS_ 20

typedef __attribute__((ext_vector_type(8))) short short8;   // bf16x8 MFMA frag
typedef __attribute__((ext_vector_type(4))) float f32x4;    // fp32 acc frag

__device__ __forceinline__ unsigned short cvt_bf16_rne(float x) {
  unsigned u = __float_as_uint(x);
  unsigned r = u + 0x7fffu + ((u >> 16) & 1u);
  return (unsigned short)(r >> 16);
}

// ---------- slot prep: fp32 -> bf16 hi/lo planes + exact fp32 ssq ----------
__global__ __launch_bounds__(64) void slot_prep_kernel(
    const float* __restrict__ slot, unsigned short* __restrict__ bhi,
    unsigned short* __restrict__ blo, float* __restrict__ ssq)
{
  const int bk = blockIdx.x;           // b*K + k
  const int t  = threadIdx.x;
  const size_t base = (size_t)bk * D_ + t * 4;
  float4 v = *(const float4*)(slot + base);
  float x[4] = {v.x, v.y, v.z, v.w};
  unsigned short h[4], lo[4];
  float sq = 0.f;
#pragma unroll
  for (int i = 0; i < 4; ++i) {
    sq = fmaf(x[i], x[i], sq);
    h[i] = cvt_bf16_rne(x[i]);
    float hf = __uint_as_float((unsigned)h[i] << 16);
    lo[i] = cvt_bf16_rne(x[i] - hf);
  }
  *(ushort4*)(bhi + base) = make_ushort4(h[0], h[1], h[2], h[3]);
  *(ushort4*)(blo + base) = make_ushort4(lo[0], lo[1], lo[2], lo[3]);
#pragma unroll
  for (int off = 32; off >= 1; off >>= 1) sq += __shfl_xor(sq, off);
  if (t == 0) ssq[bk] = sq;
}

// ---------- Phase 1: log_K via bf16-split MFMA ----------
// Block: 256 threads = 4 waves; wave w owns rows [w*64, w*64+64) x all 64 k.
// A (pixels): global fp32 -> reg convert, B (slots): LDS bf16 hi/lo, XOR-swizzled.
__global__ __launch_bounds__(256) void logk_mfma_kernel(
    const float* __restrict__ pix, const unsigned short* __restrict__ bhi,
    const unsigned short* __restrict__ blo, const float* __restrict__ ssq,
    float* __restrict__ out)
{
  __shared__ unsigned short Bl[2][K_][D_];   // 64 KB, swizzled content
  __shared__ float psq_s[256];
  __shared__ float ssq_s[K_];

  const int t  = threadIdx.x;
  const int w  = t >> 6;
  const int l  = t & 63;
  const int lr = l & 15;          // M/N index within fragment
  const int lk = l >> 4;          // k-subchunk 0..3
  const int b  = blockIdx.y;
  const int n0 = blockIdx.x * 256;

  // stage slot planes into LDS; content at linear (k,c) = source byte c ^ swz(k)
  {
    const unsigned short* pl0 = bhi + (size_t)b * K_ * D_;
    const unsigned short* pl1 = blo + (size_t)b * K_ * D_;
#pragma unroll
    for (int i = 0; i < 16; ++i) {
      int ci = i * 256 + t;            // 0..4095 16B-chunks
      int plane = ci >> 11;
      int k = (ci >> 5) & 63;
      int c = (ci & 31) << 4;          // byte col
      int srcb = c ^ ((k & 7) << 4);
      const unsigned short* sp = (plane ? pl1 : pl0) + (size_t)k * D_ + (srcb >> 1);
      short8 vv = *(const short8*)sp;
      *(short8*)((char*)(&Bl[plane][k][0]) + c) = vv;
    }
    if (t < K_) ssq_s[t] = ssq[b * K_ + t];
  }

  const float* pg = pix + ((size_t)b * N_ + n0 + w * 64 + lr) * D_ + lk * 8;

  f32x4 acc[4][4];
#pragma unroll
  for (int i = 0; i < 4; ++i)
#pragma unroll
    for (int j = 0; j < 4; ++j) acc[i][j] = (f32x4){0.f, 0.f, 0.f, 0.f};
  float psq[4] = {0.f, 0.f, 0.f, 0.f};

  float4 st[4][2];
#pragma unroll
  for (int rg = 0; rg < 4; ++rg) {
    st[rg][0] = *(const float4*)(pg + (size_t)rg * 16 * D_);
    st[rg][1] = *(const float4*)(pg + (size_t)rg * 16 * D_ + 4);
  }
  __syncthreads();

  for (int s = 0; s < 8; ++s) {
    short8 ahi[4], alo[4];
#pragma unroll
    for (int rg = 0; rg < 4; ++rg) {
      float xs[8];
      *(float4*)&xs[0] = st[rg][0];
      *(float4*)&xs[4] = st[rg][1];
#pragma unroll
      for (int j = 0; j < 8; ++j) {
        float x = xs[j];
        psq[rg] = fmaf(x, x, psq[rg]);
        unsigned short h = cvt_bf16_rne(x);
        ahi[rg][j] = (short)h;
        float hf = __uint_as_float((unsigned)h << 16);
        alo[rg][j] = (short)cvt_bf16_rne(x - hf);
      }
    }
    if (s < 7) {
#pragma unroll
      for (int rg = 0; rg < 4; ++rg) {
        st[rg][0] = *(const float4*)(pg + (size_t)rg * 16 * D_ + (s + 1) * 32);
        st[rg][1] = *(const float4*)(pg + (size_t)rg * 16 * D_ + (s + 1) * 32 + 4);
      }
    }
    short8 bh[4], bl[4];
    const int dbyte = s * 64 + lk * 16;
#pragma unroll
    for (int cg = 0; cg < 4; ++cg) {
      int krow = cg * 16 + lr;
      int off = dbyte ^ ((krow & 7) << 4);
      bh[cg] = *(const short8*)((const char*)(&Bl[0][krow][0]) + off);
      bl[cg] = *(const short8*)((const char*)(&Bl[1][krow][0]) + off);
    }
#pragma unroll
    for (int rg = 0; rg < 4; ++rg)
#pragma unroll
      for (int cg = 0; cg < 4; ++cg) {
        acc[rg][cg] = __builtin_amdgcn_mfma_f32_16x16x32_bf16(ahi[rg], bh[cg], acc[rg][cg], 0, 0, 0);
        acc[rg][cg] = __builtin_amdgcn_mfma_f32_16x16x32_bf16(ahi[rg], bl[cg], acc[rg][cg], 0, 0, 0);
        acc[rg][cg] = __builtin_amdgcn_mfma_f32_16x16x32_bf16(alo[rg], bh[cg], acc[rg][cg], 0, 0, 0);
      }
  }

  // reduce psq across the 4 lanes sharing each row (bits 4,5 of lane)
#pragma unroll
  for (int rg = 0; rg < 4; ++rg) {
    psq[rg] += __shfl_xor(psq[rg], 16);
    psq[rg] += __shfl_xor(psq[rg], 32);
  }
  if (l < 16) {
#pragma unroll
    for (int rg = 0; rg < 4; ++rg) psq_s[w * 64 + rg * 16 + lr] = psq[rg];
  }
  __syncthreads();

  float mss[4];
#pragma unroll
  for (int cg = 0; cg < 4; ++cg) mss[cg] = ssq_s[cg * 16 + lr];

  float* ob = out + ((size_t)b * N_ + n0 + w * 64) * K_;
#pragma unroll
  for (int rg = 0; rg < 4; ++rg)
#pragma unroll
    for (int q = 0; q < 4; ++q) {
      int row = rg * 16 + lk * 4 + q;
      float ps_ = psq_s[w * 64 + row];
      float* op = ob + (size_t)row * K_ + lr;
#pragma unroll
      for (int cg = 0; cg < 4; ++cg) {
        float C = ps_ + mss[cg] - 2.f * acc[rg][cg][q];
        op[cg * 16] = fmaxf(-EPS_INV * C, NEG_CLAMP);
      }
    }
}

// ---------------- Sinkhorn iteration ----------------
#define A_ROWS 128
#define A_NBLK (N_ / A_ROWS)   // 128

__global__ __launch_bounds__(256) void sink_row_kernel(
    const float* __restrict__ logk, const float* __restrict__ sw,
    const float* __restrict__ lv, float* __restrict__ lu,
    float* __restrict__ pm, float* __restrict__ ps)
{
  __shared__ float tile[A_ROWS][K_ + 1];
  __shared__ float lv_s[K_];
  __shared__ float lu_s[A_ROWS];
  __shared__ float wm[4][K_], wsum[4][K_];

  const int t = threadIdx.x;
  const int b = blockIdx.y, blk = blockIdx.x;
  const int n0 = blk * A_ROWS;
  const float* src = logk + ((size_t)b * N_ + n0) * K_;

#pragma unroll
  for (int r = 0; r < 8; ++r) {
    int u = r * 256 + t;
    int n = u >> 4, kq = u & 15;
    float4 v = *(const float4*)(src + (size_t)n * K_ + kq * 4);
    tile[n][kq * 4 + 0] = v.x; tile[n][kq * 4 + 1] = v.y;
    tile[n][kq * 4 + 2] = v.z; tile[n][kq * 4 + 3] = v.w;
  }
  if (t < K_) lv_s[t] = lv[b * K_ + t];
  __syncthreads();

  {
    const int r = t >> 1, h = t & 1;
    const int kb = 32 * h;
    float m = -INFINITY;
#pragma unroll
    for (int kk = 0; kk < 32; ++kk)
      m = fmaxf(m, tile[r][kb + kk] + lv_s[kb + kk]);
    m = fmaxf(m, __shfl_xor(m, 1));
    float s = 0.f;
#pragma unroll
    for (int kk = 0; kk < 32; ++kk)
      s += __expf(tile[r][kb + kk] + lv_s[kb + kk] - m);
    s += __shfl_xor(s, 1);
    if (h == 0) {
      float lmu = __logf(fmaxf(sw[(size_t)b * N_ + n0 + r], 1e-8f));
      float u_ = lmu - (m + __logf(s));
      lu_s[r] = u_;
      lu[(size_t)b * N_ + n0 + r] = u_;
    }
  }
  __syncthreads();

  {
    const int w = t >> 6, l = t & 63;
    float m = -INFINITY;
    for (int r = 32 * w; r < 32 * w + 32; ++r)
      m = fmaxf(m, tile[r][l] + lu_s[r]);
    float s = 0.f;
    for (int r = 32 * w; r < 32 * w + 32; ++r)
      s += __expf(tile[r][l] + lu_s[r] - m);
    wm[w][l] = m; wsum[w][l] = s;
  }
  __syncthreads();
  if (t < K_) {
    float m0 = fmaxf(fmaxf(wm[0][t], wm[1][t]), fmaxf(wm[2][t], wm[3][t]));
    float s = wsum[0][t] * __expf(wm[0][t] - m0)
            + wsum[1][t] * __expf(wm[1][t] - m0)
            + wsum[2][t] * __expf(wm[2][t] - m0)
            + wsum[3][t] * __expf(wm[3][t] - m0);
    size_t o = ((size_t)b * A_NBLK + blk) * K_ + t;
    pm[o] = m0; ps[o] = s;
  }
}

__global__ __launch_bounds__(64) void sink_col_kernel(
    const float* __restrict__ pm, const float* __restrict__ ps,
    float* __restrict__ lv)
{
  const int b = blockIdx.x, l = threadIdx.x;
  float m = -INFINITY, s = 0.f;
  for (int i = 0; i < A_NBLK; ++i) {
    size_t o = ((size_t)b * A_NBLK + i) * K_ + l;
    float mi = pm[o], si = ps[o];
    float mn = fmaxf(m, mi);
    s = s * __expf(m - mn) + si * __expf(mi - mn);
    m = mn;
  }
  lv[b * K_ + l] = LOG_NU - (m + __logf(s));
}

__global__ __launch_bounds__(256) void finalize_kernel(
    float* __restrict__ out, const float* __restrict__ lu,
    const float* __restrict__ lv)
{
  const size_t idx = (size_t)blockIdx.x * 256 + threadIdx.x;
  const size_t e0 = idx * 4;
  const int k0 = (int)(e0 & 63);
  const size_t bn = e0 >> 6;
  const int b = (int)(bn >> 14);
  const float u = lu[bn];
  const float4 v4 = *(const float4*)(lv + b * K_ + k0);
  float4 o = *(float4*)(out + e0);
  o.x = __expf(o.x + u + v4.x);
  o.y = __expf(o.y + u + v4.y);
  o.z = __expf(o.z + u + v4.z);
  o.w = __expf(o.w + u + v4.w);
  *(float4*)(out + e0) = o;
}

__global__ void init_lv_kernel(float* lv)
{
  int i = blockIdx.x * 256 + threadIdx.x;
  if (i < B_ * K_) lv[i] = 0.f;
}

extern "C" void kernel_launch(void* const* d_in, const int* in_sizes, int n_in,
                              void* d_out, int out_size, void* d_ws, size_t ws_size,
                              hipStream_t stream)
{
  const float* pix  = (const float*)d_in[0];
  const float* slot = (const float*)d_in[1];
  const float* sw   = (const float*)d_in[2];
  float* out = (float*)d_out;

  char* ws = (char*)d_ws;
  float* lu  = (float*)ws;                                      // 2 MB
  float* lv  = (float*)(ws + (size_t)B_ * N_ * 4);              // 8 KB
  float* ssq = (float*)(ws + (size_t)B_ * N_ * 4 + 16 * 1024);  // 8 KB
  float* pm  = (float*)(ws + (size_t)B_ * N_ * 4 + 64 * 1024);  // 1 MB
  float* ps  = pm + (size_t)B_ * A_NBLK * K_;                   // 1 MB
  // bf16 slot planes alias pm/ps (used only before iterations start)
  unsigned short* bhi = (unsigned short*)pm;                    // 1 MB
  unsigned short* blo = (unsigned short*)ps;                    // 1 MB

  hipLaunchKernelGGL(init_lv_kernel, dim3(8), dim3(256), 0, stream, lv);
  hipLaunchKernelGGL(slot_prep_kernel, dim3(B_ * K_), dim3(64), 0, stream,
                     slot, bhi, blo, ssq);
  hipLaunchKernelGGL(logk_mfma_kernel, dim3(N_ / 256, B_), dim3(256), 0, stream,
                     pix, bhi, blo, ssq, out);
  for (int it = 0; it < NUM_ITERS_; ++it) {
    hipLaunchKernelGGL(sink_row_kernel, dim3(A_NBLK, B_), dim3(256), 0, stream,
                       out, sw, lv, lu, pm, ps);
    hipLaunchKernelGGL(sink_col_kernel, dim3(B_), dim3(64), 0, stream,
                       pm, ps, lv);
  }
  hipLaunchKernelGGL(finalize_kernel,
                     dim3((unsigned)(((size_t)B_ * N_ * K_ / 4) / 256)), dim3(256),
                     0, stream, out, lu, lv);
}

// Round 4
// 731.458 us; speedup vs baseline: 1.8533x; 1.1576x over previous
//
#include <hip/hip_runtime.h>
#include <math.h>

#define B_ 32
#define N_ 16384
#define K_ 64
#define D_ 256
#define NUM_ITERS_ 20

#define LOG2E 1.4426950408889634f
#define F2 (20.0f * LOG2E)              // (1/eps) * log2(e)
#define CLAMP2 (-144.26950408889634f)   // -100 * log2(e)
#define LNU2 (-6.0f)                    // log2(1/64), exact
#define LK_SCALE (144.26950408889634f / 32767.0f)
#define LK_INV   (32767.0f / 144.26950408889634f)

typedef __attribute__((ext_vector_type(8))) short short8;
typedef __attribute__((ext_vector_type(4))) short short4v;
typedef __attribute__((ext_vector_type(4))) float f32x4;

__device__ __forceinline__ float exp2fast(float x) {
#if __has_builtin(__builtin_amdgcn_exp2f)
  return __builtin_amdgcn_exp2f(x);
#else
  return __expf(x * 0.6931471805599453f);
#endif
}

__device__ __forceinline__ unsigned short cvt_bf16_rne(float x) {
  unsigned u = __float_as_uint(x);
  unsigned r = u + 0x7fffu + ((u >> 16) & 1u);
  return (unsigned short)(r >> 16);
}

// merge two (max, sum) LSE partial pairs in base-2 domain
__device__ __forceinline__ void msmerge(float& m, float& s, float om, float os) {
  float mn = fmaxf(m, om);
  s = s * exp2fast(m - mn) + os * exp2fast(om - mn);
  m = mn;
}

// ---------- precompute log2(max(sw,1e-8)) ----------
__global__ __launch_bounds__(256) void lmu2_kernel(
    const float* __restrict__ sw, float* __restrict__ lmu2)
{
  size_t i = ((size_t)blockIdx.x * 256 + threadIdx.x) * 4;
  float4 v = *(const float4*)(sw + i);
  float4 o;
  o.x = __log2f(fmaxf(v.x, 1e-8f));
  o.y = __log2f(fmaxf(v.y, 1e-8f));
  o.z = __log2f(fmaxf(v.z, 1e-8f));
  o.w = __log2f(fmaxf(v.w, 1e-8f));
  *(float4*)(lmu2 + i) = o;
}

// ---------- slot prep: fp32 -> bf16 hi/lo planes + exact fp32 ssq ----------
__global__ __launch_bounds__(64) void slot_prep_kernel(
    const float* __restrict__ slot, unsigned short* __restrict__ bhi,
    unsigned short* __restrict__ blo, float* __restrict__ ssq)
{
  const int bk = blockIdx.x;
  const int t  = threadIdx.x;
  const size_t base = (size_t)bk * D_ + t * 4;
  float4 v = *(const float4*)(slot + base);
  float x[4] = {v.x, v.y, v.z, v.w};
  unsigned short h[4], lo[4];
  float sq = 0.f;
#pragma unroll
  for (int i = 0; i < 4; ++i) {
    sq = fmaf(x[i], x[i], sq);
    h[i] = cvt_bf16_rne(x[i]);
    float hf = __uint_as_float((unsigned)h[i] << 16);
    lo[i] = cvt_bf16_rne(x[i] - hf);
  }
  *(ushort4*)(bhi + base) = make_ushort4(h[0], h[1], h[2], h[3]);
  *(ushort4*)(blo + base) = make_ushort4(lo[0], lo[1], lo[2], lo[3]);
#pragma unroll
  for (int off = 32; off >= 1; off >>= 1) sq += __shfl_xor(sq, off);
  if (t == 0) ssq[bk] = sq;
}

// ---------- Phase 1: quantized log2_K via bf16-split MFMA + iter-1 fused ----------
__global__ __launch_bounds__(256) void logk_mfma_kernel(
    const float* __restrict__ pix, const unsigned short* __restrict__ bhi,
    const unsigned short* __restrict__ blo, const float* __restrict__ ssq,
    const float* __restrict__ lmu2, unsigned short* __restrict__ lk2q,
    float* __restrict__ lu, float* __restrict__ pm, float* __restrict__ ps)
{
  __shared__ unsigned short Bl[2][K_][D_];   // 64 KB; reused as transpose scratch
  __shared__ float psq_s[256];
  __shared__ float ssq_s[K_];
  __shared__ float wm_l[4][K_], ws_l[4][K_];

  const int t  = threadIdx.x;
  const int w  = t >> 6;
  const int l  = t & 63;
  const int lr = l & 15;
  const int lk = l >> 4;
  const int b  = blockIdx.y;
  const int n0 = blockIdx.x * 256;

  {
    const unsigned short* pl0 = bhi + (size_t)b * K_ * D_;
    const unsigned short* pl1 = blo + (size_t)b * K_ * D_;
#pragma unroll
    for (int i = 0; i < 16; ++i) {
      int ci = i * 256 + t;
      int plane = ci >> 11;
      int k = (ci >> 5) & 63;
      int c = (ci & 31) << 4;
      int srcb = c ^ ((k & 7) << 4);
      const unsigned short* sp = (plane ? pl1 : pl0) + (size_t)k * D_ + (srcb >> 1);
      short8 vv = *(const short8*)sp;
      *(short8*)((char*)(&Bl[plane][k][0]) + c) = vv;
    }
    if (t < K_) ssq_s[t] = ssq[b * K_ + t];
  }

  const float* pg = pix + ((size_t)b * N_ + n0 + w * 64 + lr) * D_ + lk * 8;

  f32x4 acc[4][4];
#pragma unroll
  for (int i = 0; i < 4; ++i)
#pragma unroll
    for (int j = 0; j < 4; ++j) acc[i][j] = (f32x4){0.f, 0.f, 0.f, 0.f};
  float psq[4] = {0.f, 0.f, 0.f, 0.f};

  float4 st[4][2];
#pragma unroll
  for (int rg = 0; rg < 4; ++rg) {
    st[rg][0] = *(const float4*)(pg + (size_t)rg * 16 * D_);
    st[rg][1] = *(const float4*)(pg + (size_t)rg * 16 * D_ + 4);
  }
  __syncthreads();

  for (int s = 0; s < 8; ++s) {
    short8 ahi[4], alo[4];
#pragma unroll
    for (int rg = 0; rg < 4; ++rg) {
      float xs[8];
      *(float4*)&xs[0] = st[rg][0];
      *(float4*)&xs[4] = st[rg][1];
#pragma unroll
      for (int j = 0; j < 8; ++j) {
        float x = xs[j];
        psq[rg] = fmaf(x, x, psq[rg]);
        unsigned short h = cvt_bf16_rne(x);
        ahi[rg][j] = (short)h;
        float hf = __uint_as_float((unsigned)h << 16);
        alo[rg][j] = (short)cvt_bf16_rne(x - hf);
      }
    }
    if (s < 7) {
#pragma unroll
      for (int rg = 0; rg < 4; ++rg) {
        st[rg][0] = *(const float4*)(pg + (size_t)rg * 16 * D_ + (s + 1) * 32);
        st[rg][1] = *(const float4*)(pg + (size_t)rg * 16 * D_ + (s + 1) * 32 + 4);
      }
    }
    short8 bh[4], bl[4];
    const int dbyte = s * 64 + lk * 16;
#pragma unroll
    for (int cg = 0; cg < 4; ++cg) {
      int krow = cg * 16 + lr;
      int off = dbyte ^ ((krow & 7) << 4);
      bh[cg] = *(const short8*)((const char*)(&Bl[0][krow][0]) + off);
      bl[cg] = *(const short8*)((const char*)(&Bl[1][krow][0]) + off);
    }
#pragma unroll
    for (int rg = 0; rg < 4; ++rg)
#pragma unroll
      for (int cg = 0; cg < 4; ++cg) {
        acc[rg][cg] = __builtin_amdgcn_mfma_f32_16x16x32_bf16(ahi[rg], bh[cg], acc[rg][cg], 0, 0, 0);
        acc[rg][cg] = __builtin_amdgcn_mfma_f32_16x16x32_bf16(ahi[rg], bl[cg], acc[rg][cg], 0, 0, 0);
        acc[rg][cg] = __builtin_amdgcn_mfma_f32_16x16x32_bf16(alo[rg], bh[cg], acc[rg][cg], 0, 0, 0);
      }
  }

#pragma unroll
  for (int rg = 0; rg < 4; ++rg) {
    psq[rg] += __shfl_xor(psq[rg], 16);
    psq[rg] += __shfl_xor(psq[rg], 32);
  }
  if (l < 16) {
#pragma unroll
    for (int rg = 0; rg < 4; ++rg) psq_s[w * 64 + rg * 16 + lr] = psq[rg];
  }
  __syncthreads();   // psq_s ready; all waves done reading Bl

  float mss[4];
#pragma unroll
  for (int cg = 0; cg < 4; ++cg) mss[cg] = ssq_s[cg * 16 + lr];

  // quantized log2_K values, stored back into acc
#pragma unroll
  for (int rg = 0; rg < 4; ++rg)
#pragma unroll
    for (int qq = 0; qq < 4; ++qq) {
      float ps_ = psq_s[w * 64 + rg * 16 + lk * 4 + qq];
#pragma unroll
      for (int cg = 0; cg < 4; ++cg) {
        float C = ps_ + mss[cg] - 2.f * acc[rg][cg][qq];
        float lk2 = fmaxf(-F2 * C, CLAMP2);
        int qi = __float2int_rn(lk2 * LK_INV);
        acc[rg][cg][qq] = (float)qi * LK_SCALE;
      }
    }

  // iteration-1 row update (lv = 0): per-row LSE over 64 cols
  float lu1[4][4];
  const float* lmu2p = lmu2 + (size_t)b * N_ + n0 + w * 64;
#pragma unroll
  for (int rg = 0; rg < 4; ++rg)
#pragma unroll
    for (int qq = 0; qq < 4; ++qq) {
      float a0 = acc[rg][0][qq], a1 = acc[rg][1][qq];
      float a2 = acc[rg][2][qq], a3 = acc[rg][3][qq];
      float m = fmaxf(fmaxf(a0, a1), fmaxf(a2, a3));
      float s = exp2fast(a0 - m) + exp2fast(a1 - m) + exp2fast(a2 - m) + exp2fast(a3 - m);
#pragma unroll
      for (int off = 1; off < 16; off <<= 1) {
        float om = __shfl_xor(m, off), os = __shfl_xor(s, off);
        msmerge(m, s, om, os);
      }
      int row = rg * 16 + lk * 4 + qq;
      float u2 = lmu2p[row] - (m + __log2f(s));
      lu1[rg][qq] = u2;
      if (lr == 0) lu[(size_t)b * N_ + n0 + w * 64 + row] = u2;
    }

  // iteration-1 column partials over this block's 256 rows
#pragma unroll
  for (int cg = 0; cg < 4; ++cg) {
    float m = -INFINITY;
#pragma unroll
    for (int rg = 0; rg < 4; ++rg)
#pragma unroll
      for (int qq = 0; qq < 4; ++qq)
        m = fmaxf(m, acc[rg][cg][qq] + lu1[rg][qq]);
    float s = 0.f;
#pragma unroll
    for (int rg = 0; rg < 4; ++rg)
#pragma unroll
      for (int qq = 0; qq < 4; ++qq)
        s += exp2fast(acc[rg][cg][qq] + lu1[rg][qq] - m);
    float om = __shfl_xor(m, 16), os = __shfl_xor(s, 16);
    msmerge(m, s, om, os);
    om = __shfl_xor(m, 32); os = __shfl_xor(s, 32);
    msmerge(m, s, om, os);
    if (lk == 0) { wm_l[w][cg * 16 + lr] = m; ws_l[w][cg * 16 + lr] = s; }
  }

  // transpose-stage quantized values into LDS scratch (rows padded to 72 shorts)
  unsigned short* scr = (unsigned short*)Bl + (size_t)w * 64 * 72;
#pragma unroll
  for (int rg = 0; rg < 4; ++rg)
#pragma unroll
    for (int cg = 0; cg < 4; ++cg)
#pragma unroll
      for (int qq = 0; qq < 4; ++qq) {
        int qi = __float2int_rn(acc[rg][cg][qq] * LK_INV);
        scr[(rg * 16 + lk * 4 + qq) * 72 + cg * 16 + lr] = (unsigned short)(short)qi;
      }
  __syncthreads();   // wm_l/ws_l and scratch ready

  if (t < 64) {
    float m = wm_l[0][t], s = ws_l[0][t];
    msmerge(m, s, wm_l[1][t], ws_l[1][t]);
    msmerge(m, s, wm_l[2][t], ws_l[2][t]);
    msmerge(m, s, wm_l[3][t], ws_l[3][t]);
    size_t o = ((size_t)b * 64 + blockIdx.x) * 64 + t;
    pm[o] = m; ps[o] = s;
  }

  // coalesced flush of int16 tile
  unsigned short* dst = lk2q + ((size_t)b * N_ + n0 + w * 64) * 64;
#pragma unroll
  for (int f = 0; f < 8; ++f) {
    int u = f * 64 + l;
    int row = u >> 3, kq = u & 7;
    short8 v8 = *(const short8*)(scr + row * 72 + kq * 8);
    *(short8*)(dst + row * 64 + kq * 8) = v8;
  }
}

// ---------- fused iteration: merge prev col-partials -> lv; row update; col partials ----------
template <int NBLK_IN>
__global__ __launch_bounds__(256) void fused_row_kernel(
    const unsigned short* __restrict__ lk2q, const float* __restrict__ lmu2,
    const float* __restrict__ pm_in, const float* __restrict__ ps_in,
    float* __restrict__ pm_out, float* __restrict__ ps_out,
    float* __restrict__ lu)
{
  __shared__ float tile[128][65];
  __shared__ float lv_s[64];
  __shared__ float lu_s[128];
  __shared__ float wm[4][64], wsum[4][64];

  const int t = threadIdx.x;
  const int b = blockIdx.y, blk = blockIdx.x;
  const int n0 = blk * 128;

  // prologue: redundant per-block merge of previous iteration's partials
  {
    const int k = t & 63, g = t >> 6;
    constexpr int CH = NBLK_IN / 4;
    float m = -INFINITY, s = 0.f;
    const float* pmi = pm_in + ((size_t)b * NBLK_IN + g * CH) * 64 + k;
    const float* psi = ps_in + ((size_t)b * NBLK_IN + g * CH) * 64 + k;
#pragma unroll
    for (int i = 0; i < CH; ++i) msmerge(m, s, pmi[i * 64], psi[i * 64]);
    wm[g][k] = m; wsum[g][k] = s;
  }
  // tile load: int16 -> fp32 dequant
  {
    const unsigned short* src = lk2q + ((size_t)b * N_ + n0) * 64;
#pragma unroll
    for (int i = 0; i < 4; ++i) {
      int u = i * 256 + t;
      int n = u >> 3, kq = u & 7;
      short8 v = *(const short8*)(src + n * 64 + kq * 8);
#pragma unroll
      for (int j = 0; j < 8; ++j) tile[n][kq * 8 + j] = (float)v[j] * LK_SCALE;
    }
  }
  __syncthreads();
  if (t < 64) {
    float m = wm[0][t], s = wsum[0][t];
    msmerge(m, s, wm[1][t], wsum[1][t]);
    msmerge(m, s, wm[2][t], wsum[2][t]);
    msmerge(m, s, wm[3][t], wsum[3][t]);
    lv_s[t] = LNU2 - (m + __log2f(s));
  }
  __syncthreads();

  // row update
  {
    const int r = t >> 1, h = t & 1, kb = 32 * h;
    float m = -INFINITY;
#pragma unroll
    for (int kk = 0; kk < 32; ++kk)
      m = fmaxf(m, tile[r][kb + kk] + lv_s[kb + kk]);
    m = fmaxf(m, __shfl_xor(m, 1));
    float s = 0.f;
#pragma unroll
    for (int kk = 0; kk < 32; ++kk)
      s += exp2fast(tile[r][kb + kk] + lv_s[kb + kk] - m);
    s += __shfl_xor(s, 1);
    if (h == 0) {
      float u2 = lmu2[(size_t)b * N_ + n0 + r] - (m + __log2f(s));
      lu_s[r] = u2;
      lu[(size_t)b * N_ + n0 + r] = u2;
    }
  }
  __syncthreads();

  // column partials with fresh lu
  {
    const int w = t >> 6, l = t & 63;
    float m = -INFINITY;
    for (int r = 32 * w; r < 32 * w + 32; ++r)
      m = fmaxf(m, tile[r][l] + lu_s[r]);
    float s = 0.f;
    for (int r = 32 * w; r < 32 * w + 32; ++r)
      s += exp2fast(tile[r][l] + lu_s[r] - m);
    wm[w][l] = m; wsum[w][l] = s;
  }
  __syncthreads();
  if (t < 64) {
    float m = wm[0][t], s = wsum[0][t];
    msmerge(m, s, wm[1][t], wsum[1][t]);
    msmerge(m, s, wm[2][t], wsum[2][t]);
    msmerge(m, s, wm[3][t], wsum[3][t]);
    size_t o = ((size_t)b * 128 + blk) * 64 + t;
    pm_out[o] = m; ps_out[o] = s;
  }
}

// ---------- final column merge -> lv20 ----------
__global__ __launch_bounds__(64) void col_merge_kernel(
    const float* __restrict__ pm, const float* __restrict__ ps,
    float* __restrict__ lvf)
{
  const int bid = blockIdx.x;   // b*64 + k
  const int b = bid >> 6, k = bid & 63;
  const int j = threadIdx.x;
  size_t base = ((size_t)b * 128) * 64 + k;
  float m = pm[base + (size_t)j * 64], s = ps[base + (size_t)j * 64];
  msmerge(m, s, pm[base + (size_t)(j + 64) * 64], ps[base + (size_t)(j + 64) * 64]);
#pragma unroll
  for (int off = 32; off >= 1; off >>= 1) {
    float om = __shfl_xor(m, off), os = __shfl_xor(s, off);
    msmerge(m, s, om, os);
  }
  if (j == 0) lvf[bid] = LNU2 - (m + __log2f(s));
}

// ---------- finalize: out = 2^(lu + lk2 + lv) ----------
__global__ __launch_bounds__(256) void finalize_kernel(
    const unsigned short* __restrict__ lk2q, const float* __restrict__ lu,
    const float* __restrict__ lvf, float* __restrict__ out)
{
  const size_t idx = (size_t)blockIdx.x * 256 + threadIdx.x;
  const size_t e0 = idx * 4;
  const int k0 = (int)(e0 & 63);
  const size_t bn = e0 >> 6;
  const int b = (int)(bn >> 14);
  const float u = lu[bn];
  const float4 v4 = *(const float4*)(lvf + b * 64 + k0);
  short4v qv = *(const short4v*)((const short*)lk2q + e0);
  float4 o;
  o.x = exp2fast((float)qv[0] * LK_SCALE + u + v4.x);
  o.y = exp2fast((float)qv[1] * LK_SCALE + u + v4.y);
  o.z = exp2fast((float)qv[2] * LK_SCALE + u + v4.z);
  o.w = exp2fast((float)qv[3] * LK_SCALE + u + v4.w);
  *(float4*)(out + e0) = o;
}

extern "C" void kernel_launch(void* const* d_in, const int* in_sizes, int n_in,
                              void* d_out, int out_size, void* d_ws, size_t ws_size,
                              hipStream_t stream)
{
  const float* pix  = (const float*)d_in[0];
  const float* slot = (const float*)d_in[1];
  const float* sw   = (const float*)d_in[2];
  float* out = (float*)d_out;

  char* ws = (char*)d_ws;
  float* lu    = (float*)(ws);                        // 2 MB
  float* lmu2  = (float*)(ws + (2ull << 20));         // 2 MB
  float* lvf   = (float*)(ws + (4ull << 20));         // 8 KB
  float* ssq   = (float*)(ws + (4ull << 20) + 65536); // 8 KB
  float* pmA   = (float*)(ws + (5ull << 20));         // 1 MB
  float* psA   = (float*)(ws + (6ull << 20));
  float* pmB   = (float*)(ws + (7ull << 20));
  float* psB   = (float*)(ws + (8ull << 20));
  unsigned short* bhi  = (unsigned short*)(ws + (9ull << 20));   // 1 MB
  unsigned short* blo  = (unsigned short*)(ws + (10ull << 20));  // 1 MB
  unsigned short* lk2q = (unsigned short*)(ws + (16ull << 20));  // 67 MB

  lmu2_kernel<<<512, 256, 0, stream>>>(sw, lmu2);
  slot_prep_kernel<<<B_ * K_, 64, 0, stream>>>(slot, bhi, blo, ssq);
  logk_mfma_kernel<<<dim3(N_ / 256, B_), 256, 0, stream>>>(
      pix, bhi, blo, ssq, lmu2, lk2q, lu, pmA, psA);

  float *im = pmA, *is = psA, *om = pmB, *os = psB;
  for (int it = 2; it <= NUM_ITERS_; ++it) {
    if (it == 2)
      fused_row_kernel<64><<<dim3(128, B_), 256, 0, stream>>>(
          lk2q, lmu2, im, is, om, os, lu);
    else
      fused_row_kernel<128><<<dim3(128, B_), 256, 0, stream>>>(
          lk2q, lmu2, im, is, om, os, lu);
    float* tm = im; im = om; om = tm;
    float* ts = is; is = os; os = ts;
  }
  col_merge_kernel<<<B_ * K_, 64, 0, stream>>>(im, is, lvf);
  finalize_kernel<<<(unsigned)(((size_t)B_ * N_ * K_ / 4) / 256), 256, 0, stream>>>(
      lk2q, lu, lvf, out);
}

// Round 5
// 511.973 us; speedup vs baseline: 2.6478x; 1.4287x over previous
//
#include <hip/hip_runtime.h>
#include <math.h>

#define B_ 32
#define N_ 16384
#define K_ 64
#define D_ 256
#define NUM_ITERS_ 20

#define F2 (20.0f * 1.4426950408889634f)   // (1/eps)*log2(e)
#define CLAMP2 (-144.26950408889634f)      // -100*log2(e)
#define NUW 0.015625f                      // 1/64

typedef __attribute__((ext_vector_type(8))) short short8;
typedef _Float16 half8 __attribute__((ext_vector_type(8)));
typedef __attribute__((ext_vector_type(4))) float f32x4;

__device__ __forceinline__ float exp2fast(float x) {
#if __has_builtin(__builtin_amdgcn_exp2f)
  return __builtin_amdgcn_exp2f(x);
#else
  return __expf(x * 0.6931471805599453f);
#endif
}

__device__ __forceinline__ unsigned short cvt_bf16_rne(float x) {
  unsigned u = __float_as_uint(x);
  unsigned r = u + 0x7fffu + ((u >> 16) & 1u);
  return (unsigned short)(r >> 16);
}

// ---------- slot prep: fp32 -> bf16 hi/lo planes + exact fp32 ssq ----------
__global__ __launch_bounds__(64) void slot_prep_kernel(
    const float* __restrict__ slot, unsigned short* __restrict__ bhi,
    unsigned short* __restrict__ blo, float* __restrict__ ssq)
{
  const int bk = blockIdx.x;
  const int t  = threadIdx.x;
  const size_t base = (size_t)bk * D_ + t * 4;
  float4 v = *(const float4*)(slot + base);
  float x[4] = {v.x, v.y, v.z, v.w};
  unsigned short h[4], lo[4];
  float sq = 0.f;
#pragma unroll
  for (int i = 0; i < 4; ++i) {
    sq = fmaf(x[i], x[i], sq);
    h[i] = cvt_bf16_rne(x[i]);
    float hf = __uint_as_float((unsigned)h[i] << 16);
    lo[i] = cvt_bf16_rne(x[i] - hf);
  }
  *(ushort4*)(bhi + base) = make_ushort4(h[0], h[1], h[2], h[3]);
  *(ushort4*)(blo + base) = make_ushort4(lo[0], lo[1], lo[2], lo[3]);
#pragma unroll
  for (int off = 32; off >= 1; off >>= 1) sq += __shfl_xor(sq, off);
  if (t == 0) ssq[bk] = sq;
}

// ---------- Phase 1: E = 2^(log2K - rowmax) (fp16) + fused iteration 1 ----------
__global__ __launch_bounds__(256) void logk_mfma_kernel(
    const float* __restrict__ pix, const unsigned short* __restrict__ bhi,
    const unsigned short* __restrict__ blo, const float* __restrict__ ssq,
    const float* __restrict__ sw, _Float16* __restrict__ E,
    float* __restrict__ Tp)
{
  __shared__ unsigned short Bl[2][K_][D_];   // 64 KB; reused as fp16 transpose scratch
  __shared__ float psq_s[256];               // psq, then row sums s
  __shared__ float ssq_s[K_];
  __shared__ float wm_l[4][K_];
  __shared__ float W_l[256];

  const int t  = threadIdx.x;
  const int w  = t >> 6;
  const int l  = t & 63;
  const int lr = l & 15;
  const int lk = l >> 4;
  const int b  = blockIdx.y;
  const int n0 = blockIdx.x * 256;

  {
    const unsigned short* pl0 = bhi + (size_t)b * K_ * D_;
    const unsigned short* pl1 = blo + (size_t)b * K_ * D_;
#pragma unroll
    for (int i = 0; i < 16; ++i) {
      int ci = i * 256 + t;
      int plane = ci >> 11;
      int k = (ci >> 5) & 63;
      int c = (ci & 31) << 4;
      int srcb = c ^ ((k & 7) << 4);
      const unsigned short* sp = (plane ? pl1 : pl0) + (size_t)k * D_ + (srcb >> 1);
      short8 vv = *(const short8*)sp;
      *(short8*)((char*)(&Bl[plane][k][0]) + c) = vv;
    }
    if (t < K_) ssq_s[t] = ssq[b * K_ + t];
  }

  const float* pg = pix + ((size_t)b * N_ + n0 + w * 64 + lr) * D_ + lk * 8;

  f32x4 acc[4][4];
#pragma unroll
  for (int i = 0; i < 4; ++i)
#pragma unroll
    for (int j = 0; j < 4; ++j) acc[i][j] = (f32x4){0.f, 0.f, 0.f, 0.f};
  float psq[4] = {0.f, 0.f, 0.f, 0.f};

  float4 st[4][2];
#pragma unroll
  for (int rg = 0; rg < 4; ++rg) {
    st[rg][0] = *(const float4*)(pg + (size_t)rg * 16 * D_);
    st[rg][1] = *(const float4*)(pg + (size_t)rg * 16 * D_ + 4);
  }
  __syncthreads();

  for (int s = 0; s < 8; ++s) {
    short8 ahi[4], alo[4];
#pragma unroll
    for (int rg = 0; rg < 4; ++rg) {
      float xs[8];
      *(float4*)&xs[0] = st[rg][0];
      *(float4*)&xs[4] = st[rg][1];
#pragma unroll
      for (int j = 0; j < 8; ++j) {
        float x = xs[j];
        psq[rg] = fmaf(x, x, psq[rg]);
        unsigned short h = cvt_bf16_rne(x);
        ahi[rg][j] = (short)h;
        float hf = __uint_as_float((unsigned)h << 16);
        alo[rg][j] = (short)cvt_bf16_rne(x - hf);
      }
    }
    if (s < 7) {
#pragma unroll
      for (int rg = 0; rg < 4; ++rg) {
        st[rg][0] = *(const float4*)(pg + (size_t)rg * 16 * D_ + (s + 1) * 32);
        st[rg][1] = *(const float4*)(pg + (size_t)rg * 16 * D_ + (s + 1) * 32 + 4);
      }
    }
    short8 bh[4], bl[4];
    const int dbyte = s * 64 + lk * 16;
#pragma unroll
    for (int cg = 0; cg < 4; ++cg) {
      int krow = cg * 16 + lr;
      int off = dbyte ^ ((krow & 7) << 4);
      bh[cg] = *(const short8*)((const char*)(&Bl[0][krow][0]) + off);
      bl[cg] = *(const short8*)((const char*)(&Bl[1][krow][0]) + off);
    }
#pragma unroll
    for (int rg = 0; rg < 4; ++rg)
#pragma unroll
      for (int cg = 0; cg < 4; ++cg) {
        acc[rg][cg] = __builtin_amdgcn_mfma_f32_16x16x32_bf16(ahi[rg], bh[cg], acc[rg][cg], 0, 0, 0);
        acc[rg][cg] = __builtin_amdgcn_mfma_f32_16x16x32_bf16(ahi[rg], bl[cg], acc[rg][cg], 0, 0, 0);
        acc[rg][cg] = __builtin_amdgcn_mfma_f32_16x16x32_bf16(alo[rg], bh[cg], acc[rg][cg], 0, 0, 0);
      }
  }

#pragma unroll
  for (int rg = 0; rg < 4; ++rg) {
    psq[rg] += __shfl_xor(psq[rg], 16);
    psq[rg] += __shfl_xor(psq[rg], 32);
  }
  if (l < 16) {
#pragma unroll
    for (int rg = 0; rg < 4; ++rg) psq_s[w * 64 + rg * 16 + lr] = psq[rg];
  }
  __syncthreads();   // psq_s ready; all waves done reading Bl (scr reuse safe)

  float mss[4];
#pragma unroll
  for (int cg = 0; cg < 4; ++cg) mss[cg] = ssq_s[cg * 16 + lr];

  // log2_K into acc
#pragma unroll
  for (int rg = 0; rg < 4; ++rg)
#pragma unroll
    for (int qq = 0; qq < 4; ++qq) {
      float ps_ = psq_s[w * 64 + rg * 16 + lk * 4 + qq];
#pragma unroll
      for (int cg = 0; cg < 4; ++cg) {
        float C = ps_ + mss[cg] - 2.f * acc[rg][cg][qq];
        acc[rg][cg][qq] = fmaxf(-F2 * C, CLAMP2);
      }
    }

  // per-row max -> E = 2^(lk - rmax); row sums s (= iter-1 row LSE with V=1)
#pragma unroll
  for (int rg = 0; rg < 4; ++rg)
#pragma unroll
    for (int qq = 0; qq < 4; ++qq) {
      float m = fmaxf(fmaxf(acc[rg][0][qq], acc[rg][1][qq]),
                      fmaxf(acc[rg][2][qq], acc[rg][3][qq]));
      m = fmaxf(m, __shfl_xor(m, 1));
      m = fmaxf(m, __shfl_xor(m, 2));
      m = fmaxf(m, __shfl_xor(m, 4));
      m = fmaxf(m, __shfl_xor(m, 8));
#pragma unroll
      for (int cg = 0; cg < 4; ++cg)
        acc[rg][cg][qq] = exp2fast(acc[rg][cg][qq] - m);
      float s = acc[rg][0][qq] + acc[rg][1][qq] + acc[rg][2][qq] + acc[rg][3][qq];
      s += __shfl_xor(s, 1);
      s += __shfl_xor(s, 2);
      s += __shfl_xor(s, 4);
      s += __shfl_xor(s, 8);
      if (lr == 0) psq_s[w * 64 + rg * 16 + lk * 4 + qq] = s;  // own-wave segment
    }

  // W_n = max(sw,1e-8)/s_n  (row t of this block; same-wave LDS segment)
  {
    float sv = psq_s[t];
    float muw = fmaxf(sw[(size_t)b * N_ + n0 + t], 1e-8f);
    W_l[t] = muw / sv;
  }

  // iter-1 column partials: T_k = sum_n E_nk * W_n over this block's 256 rows
  float Wv[4][4];
#pragma unroll
  for (int rg = 0; rg < 4; ++rg)
#pragma unroll
    for (int qq = 0; qq < 4; ++qq)
      Wv[rg][qq] = W_l[w * 64 + rg * 16 + lk * 4 + qq];
#pragma unroll
  for (int cg = 0; cg < 4; ++cg) {
    float Tt = 0.f;
#pragma unroll
    for (int rg = 0; rg < 4; ++rg)
#pragma unroll
      for (int qq = 0; qq < 4; ++qq)
        Tt = fmaf(acc[rg][cg][qq], Wv[rg][qq], Tt);
    Tt += __shfl_xor(Tt, 16);
    Tt += __shfl_xor(Tt, 32);
    if (lk == 0) wm_l[w][cg * 16 + lr] = Tt;
  }

  // transpose-stage E (fp16) into LDS scratch (rows padded to 72 halves)
  _Float16* scr = (_Float16*)Bl + (size_t)w * 64 * 72;
#pragma unroll
  for (int rg = 0; rg < 4; ++rg)
#pragma unroll
    for (int cg = 0; cg < 4; ++cg)
#pragma unroll
      for (int qq = 0; qq < 4; ++qq)
        scr[(rg * 16 + lk * 4 + qq) * 72 + cg * 16 + lr] = (_Float16)acc[rg][cg][qq];
  __syncthreads();

  if (t < 64) {
    float T = wm_l[0][t] + wm_l[1][t] + wm_l[2][t] + wm_l[3][t];
    Tp[((size_t)b * 64 + blockIdx.x) * 64 + t] = T;
  }

  // coalesced flush of fp16 E tile
  _Float16* dst = E + ((size_t)b * N_ + n0 + w * 64) * 64;
#pragma unroll
  for (int f = 0; f < 8; ++f) {
    int u = f * 64 + l;
    int row = u >> 3, kq = u & 7;
    half8 v8 = *(const half8*)(scr + row * 72 + kq * 8);
    *(half8*)(dst + row * 64 + kq * 8) = v8;
  }
}

// ---------- fused iteration (linear space, no transcendentals) ----------
// merge prev T partials -> V; row: s = E.V, W = muw/s; col partials: T = E^T.W
template <int NBLK_IN>
__global__ __launch_bounds__(256) void iter_kernel(
    const _Float16* __restrict__ E, const float* __restrict__ sw,
    const float* __restrict__ Tin, float* __restrict__ Tout,
    float* __restrict__ W)
{
  __shared__ float tile[128][65];
  __shared__ float V_s[64];
  __shared__ float W_s[128];
  __shared__ float wT[4][64];

  const int t = threadIdx.x;
  const int b = blockIdx.y, blk = blockIdx.x;
  const int n0 = blk * 128;

  {
    const int k = t & 63, g = t >> 6;
    constexpr int CH = NBLK_IN / 4;
    float tp = 0.f;
    const float* ti = Tin + ((size_t)b * NBLK_IN + g * CH) * 64 + k;
#pragma unroll
    for (int i = 0; i < CH; ++i) tp += ti[i * 64];
    wT[g][k] = tp;
  }
  {
    const _Float16* src = E + ((size_t)b * N_ + n0) * 64;
#pragma unroll
    for (int i = 0; i < 4; ++i) {
      int u = i * 256 + t;
      int n = u >> 3, kq = u & 7;
      half8 v = *(const half8*)(src + (size_t)n * 64 + kq * 8);
#pragma unroll
      for (int j = 0; j < 8; ++j) tile[n][kq * 8 + j] = (float)v[j];
    }
  }
  __syncthreads();
  if (t < 64) V_s[t] = NUW / (wT[0][t] + wT[1][t] + wT[2][t] + wT[3][t]);
  __syncthreads();

  {
    const int r = t >> 1, h = t & 1, kb = 32 * h;
    float s = 0.f;
#pragma unroll
    for (int kk = 0; kk < 32; ++kk) s = fmaf(tile[r][kb + kk], V_s[kb + kk], s);
    s += __shfl_xor(s, 1);
    if (h == 0) {
      float Wv = fmaxf(sw[(size_t)b * N_ + n0 + r], 1e-8f) / s;
      W_s[r] = Wv;
      W[(size_t)b * N_ + n0 + r] = Wv;
    }
  }
  __syncthreads();

  {
    const int wv = t >> 6, l = t & 63;
    float T = 0.f;
#pragma unroll
    for (int rr = 0; rr < 32; ++rr)
      T = fmaf(tile[32 * wv + rr][l], W_s[32 * wv + rr], T);
    wT[wv][l] = T;
  }
  __syncthreads();
  if (t < 64)
    Tout[((size_t)b * 128 + blk) * 64 + t] = wT[0][t] + wT[1][t] + wT[2][t] + wT[3][t];
}

// ---------- final column merge -> V ----------
__global__ __launch_bounds__(64) void col_merge_kernel(
    const float* __restrict__ Tin, float* __restrict__ Vf)
{
  const int bid = blockIdx.x;   // b*64 + k
  const int b = bid >> 6, k = bid & 63;
  const int j = threadIdx.x;
  size_t base = (size_t)b * 128 * 64 + k;
  float T = Tin[base + (size_t)j * 64] + Tin[base + (size_t)(j + 64) * 64];
#pragma unroll
  for (int off = 32; off >= 1; off >>= 1) T += __shfl_xor(T, off);
  if (j == 0) Vf[bid] = NUW / T;
}

// ---------- finalize: P = W_n * E_nk * V_k ----------
__global__ __launch_bounds__(256) void finalize_kernel(
    const _Float16* __restrict__ E, const float* __restrict__ W,
    const float* __restrict__ Vf, float* __restrict__ out)
{
  const size_t tid = (size_t)blockIdx.x * 256 + threadIdx.x;
  const size_t e0 = tid * 8;
  const int k0 = (int)(e0 & 63);
  const size_t bn = e0 >> 6;
  const int b = (int)(bn >> 14);
  const float Wv = W[bn];
  half8 ev = *(const half8*)(E + e0);
  float4 v0 = *(const float4*)(Vf + b * 64 + k0);
  float4 v1 = *(const float4*)(Vf + b * 64 + k0 + 4);
  float4 o0, o1;
  o0.x = Wv * (float)ev[0] * v0.x;
  o0.y = Wv * (float)ev[1] * v0.y;
  o0.z = Wv * (float)ev[2] * v0.z;
  o0.w = Wv * (float)ev[3] * v0.w;
  o1.x = Wv * (float)ev[4] * v1.x;
  o1.y = Wv * (float)ev[5] * v1.y;
  o1.z = Wv * (float)ev[6] * v1.z;
  o1.w = Wv * (float)ev[7] * v1.w;
  *(float4*)(out + e0) = o0;
  *(float4*)(out + e0 + 4) = o1;
}

extern "C" void kernel_launch(void* const* d_in, const int* in_sizes, int n_in,
                              void* d_out, int out_size, void* d_ws, size_t ws_size,
                              hipStream_t stream)
{
  const float* pix  = (const float*)d_in[0];
  const float* slot = (const float*)d_in[1];
  const float* sw   = (const float*)d_in[2];
  float* out = (float*)d_out;

  char* ws = (char*)d_ws;
  float* W    = (float*)ws;                          // 2 MB
  float* Vf   = (float*)(ws + (2ull << 20));         // 8 KB
  float* ssq  = (float*)(ws + (2ull << 20) + 65536); // 8 KB
  float* TpA  = (float*)(ws + (3ull << 20));         // 1 MB
  float* TpB  = (float*)(ws + (4ull << 20));         // 1 MB
  unsigned short* bhi = (unsigned short*)(ws + (5ull << 20));  // 1 MB
  unsigned short* blo = (unsigned short*)(ws + (6ull << 20));  // 1 MB
  _Float16* E = (_Float16*)(ws + (8ull << 20));      // 67 MB

  slot_prep_kernel<<<B_ * K_, 64, 0, stream>>>(slot, bhi, blo, ssq);
  logk_mfma_kernel<<<dim3(N_ / 256, B_), 256, 0, stream>>>(
      pix, bhi, blo, ssq, sw, E, TpA);

  float *im = TpA, *om = TpB;
  for (int it = 2; it <= NUM_ITERS_; ++it) {
    if (it == 2)
      iter_kernel<64><<<dim3(128, B_), 256, 0, stream>>>(E, sw, im, om, W);
    else
      iter_kernel<128><<<dim3(128, B_), 256, 0, stream>>>(E, sw, im, om, W);
    float* tmp = im; im = om; om = tmp;
  }
  col_merge_kernel<<<B_ * K_, 64, 0, stream>>>(im, Vf);
  finalize_kernel<<<(unsigned)(((size_t)B_ * N_ * K_ / 8) / 256), 256, 0, stream>>>(
      E, W, Vf, out);
}

// Round 6
// 481.494 us; speedup vs baseline: 2.8154x; 1.0633x over previous
//
#include <hip/hip_runtime.h>
#include <math.h>

#define B_ 32
#define N_ 16384
#define K_ 64
#define D_ 256
#define NUM_ITERS_ 20

#define F2 (20.0f * 1.4426950408889634f)   // (1/eps)*log2(e)
#define CLAMP2 (-144.26950408889634f)      // -100*log2(e)
#define NUW 0.015625f                      // 1/64

typedef __attribute__((ext_vector_type(8))) short short8;
typedef _Float16 half8 __attribute__((ext_vector_type(8)));
typedef __attribute__((ext_vector_type(4))) float f32x4;

__device__ __forceinline__ float exp2fast(float x) {
#if __has_builtin(__builtin_amdgcn_exp2f)
  return __builtin_amdgcn_exp2f(x);
#else
  return __expf(x * 0.6931471805599453f);
#endif
}

__device__ __forceinline__ unsigned short cvt_bf16_rne(float x) {
  unsigned u = __float_as_uint(x);
  unsigned r = u + 0x7fffu + ((u >> 16) & 1u);
  return (unsigned short)(r >> 16);
}

__device__ __forceinline__ float cvt_lo(unsigned u) {
  return (float)*reinterpret_cast<const _Float16*>(&u);
}
__device__ __forceinline__ float cvt_hi(unsigned u) {
  unsigned short h = (unsigned short)(u >> 16);
  return (float)*reinterpret_cast<const _Float16*>(&h);
}

// ---------- slot prep: fp32 -> bf16 hi/lo planes + exact fp32 ssq ----------
__global__ __launch_bounds__(64) void slot_prep_kernel(
    const float* __restrict__ slot, unsigned short* __restrict__ bhi,
    unsigned short* __restrict__ blo, float* __restrict__ ssq)
{
  const int bk = blockIdx.x;
  const int t  = threadIdx.x;
  const size_t base = (size_t)bk * D_ + t * 4;
  float4 v = *(const float4*)(slot + base);
  float x[4] = {v.x, v.y, v.z, v.w};
  unsigned short h[4], lo[4];
  float sq = 0.f;
#pragma unroll
  for (int i = 0; i < 4; ++i) {
    sq = fmaf(x[i], x[i], sq);
    h[i] = cvt_bf16_rne(x[i]);
    float hf = __uint_as_float((unsigned)h[i] << 16);
    lo[i] = cvt_bf16_rne(x[i] - hf);
  }
  *(ushort4*)(bhi + base) = make_ushort4(h[0], h[1], h[2], h[3]);
  *(ushort4*)(blo + base) = make_ushort4(lo[0], lo[1], lo[2], lo[3]);
#pragma unroll
  for (int off = 32; off >= 1; off >>= 1) sq += __shfl_xor(sq, off);
  if (t == 0) ssq[bk] = sq;
}

// ---------- Phase 1: E = 2^(log2K - rowmax) (fp16) + fused iteration 1 ----------
__global__ __launch_bounds__(256) void logk_mfma_kernel(
    const float* __restrict__ pix, const unsigned short* __restrict__ bhi,
    const unsigned short* __restrict__ blo, const float* __restrict__ ssq,
    const float* __restrict__ sw, _Float16* __restrict__ E,
    float* __restrict__ Tp)
{
  __shared__ unsigned short Bl[2][K_][D_];   // 64 KB; reused as fp16 transpose scratch
  __shared__ float psq_s[256];               // psq, then row sums s
  __shared__ float ssq_s[K_];
  __shared__ float wm_l[4][K_];
  __shared__ float W_l[256];

  const int t  = threadIdx.x;
  const int w  = t >> 6;
  const int l  = t & 63;
  const int lr = l & 15;
  const int lk = l >> 4;
  const int b  = blockIdx.y;
  const int n0 = blockIdx.x * 256;

  {
    const unsigned short* pl0 = bhi + (size_t)b * K_ * D_;
    const unsigned short* pl1 = blo + (size_t)b * K_ * D_;
#pragma unroll
    for (int i = 0; i < 16; ++i) {
      int ci = i * 256 + t;
      int plane = ci >> 11;
      int k = (ci >> 5) & 63;
      int c = (ci & 31) << 4;
      int srcb = c ^ ((k & 7) << 4);
      const unsigned short* sp = (plane ? pl1 : pl0) + (size_t)k * D_ + (srcb >> 1);
      short8 vv = *(const short8*)sp;
      *(short8*)((char*)(&Bl[plane][k][0]) + c) = vv;
    }
    if (t < K_) ssq_s[t] = ssq[b * K_ + t];
  }

  const float* pg = pix + ((size_t)b * N_ + n0 + w * 64 + lr) * D_ + lk * 8;

  f32x4 acc[4][4];
#pragma unroll
  for (int i = 0; i < 4; ++i)
#pragma unroll
    for (int j = 0; j < 4; ++j) acc[i][j] = (f32x4){0.f, 0.f, 0.f, 0.f};
  float psq[4] = {0.f, 0.f, 0.f, 0.f};

  float4 st[4][2];
#pragma unroll
  for (int rg = 0; rg < 4; ++rg) {
    st[rg][0] = *(const float4*)(pg + (size_t)rg * 16 * D_);
    st[rg][1] = *(const float4*)(pg + (size_t)rg * 16 * D_ + 4);
  }
  __syncthreads();

  for (int s = 0; s < 8; ++s) {
    short8 ahi[4], alo[4];
#pragma unroll
    for (int rg = 0; rg < 4; ++rg) {
      float xs[8];
      *(float4*)&xs[0] = st[rg][0];
      *(float4*)&xs[4] = st[rg][1];
#pragma unroll
      for (int j = 0; j < 8; ++j) {
        float x = xs[j];
        psq[rg] = fmaf(x, x, psq[rg]);
        unsigned short h = cvt_bf16_rne(x);
        ahi[rg][j] = (short)h;
        float hf = __uint_as_float((unsigned)h << 16);
        alo[rg][j] = (short)cvt_bf16_rne(x - hf);
      }
    }
    if (s < 7) {
#pragma unroll
      for (int rg = 0; rg < 4; ++rg) {
        st[rg][0] = *(const float4*)(pg + (size_t)rg * 16 * D_ + (s + 1) * 32);
        st[rg][1] = *(const float4*)(pg + (size_t)rg * 16 * D_ + (s + 1) * 32 + 4);
      }
    }
    short8 bh[4], bl[4];
    const int dbyte = s * 64 + lk * 16;
#pragma unroll
    for (int cg = 0; cg < 4; ++cg) {
      int krow = cg * 16 + lr;
      int off = dbyte ^ ((krow & 7) << 4);
      bh[cg] = *(const short8*)((const char*)(&Bl[0][krow][0]) + off);
      bl[cg] = *(const short8*)((const char*)(&Bl[1][krow][0]) + off);
    }
#pragma unroll
    for (int rg = 0; rg < 4; ++rg)
#pragma unroll
      for (int cg = 0; cg < 4; ++cg) {
        acc[rg][cg] = __builtin_amdgcn_mfma_f32_16x16x32_bf16(ahi[rg], bh[cg], acc[rg][cg], 0, 0, 0);
        acc[rg][cg] = __builtin_amdgcn_mfma_f32_16x16x32_bf16(ahi[rg], bl[cg], acc[rg][cg], 0, 0, 0);
        acc[rg][cg] = __builtin_amdgcn_mfma_f32_16x16x32_bf16(alo[rg], bh[cg], acc[rg][cg], 0, 0, 0);
      }
  }

#pragma unroll
  for (int rg = 0; rg < 4; ++rg) {
    psq[rg] += __shfl_xor(psq[rg], 16);
    psq[rg] += __shfl_xor(psq[rg], 32);
  }
  if (l < 16) {
#pragma unroll
    for (int rg = 0; rg < 4; ++rg) psq_s[w * 64 + rg * 16 + lr] = psq[rg];
  }
  __syncthreads();   // psq_s ready; all waves done reading Bl (scr reuse safe)

  float mss[4];
#pragma unroll
  for (int cg = 0; cg < 4; ++cg) mss[cg] = ssq_s[cg * 16 + lr];

  // log2_K into acc
#pragma unroll
  for (int rg = 0; rg < 4; ++rg)
#pragma unroll
    for (int qq = 0; qq < 4; ++qq) {
      float ps_ = psq_s[w * 64 + rg * 16 + lk * 4 + qq];
#pragma unroll
      for (int cg = 0; cg < 4; ++cg) {
        float C = ps_ + mss[cg] - 2.f * acc[rg][cg][qq];
        acc[rg][cg][qq] = fmaxf(-F2 * C, CLAMP2);
      }
    }

  // per-row max -> E = 2^(lk - rmax); row sums s (= iter-1 row pass with V=1)
#pragma unroll
  for (int rg = 0; rg < 4; ++rg)
#pragma unroll
    for (int qq = 0; qq < 4; ++qq) {
      float m = fmaxf(fmaxf(acc[rg][0][qq], acc[rg][1][qq]),
                      fmaxf(acc[rg][2][qq], acc[rg][3][qq]));
      m = fmaxf(m, __shfl_xor(m, 1));
      m = fmaxf(m, __shfl_xor(m, 2));
      m = fmaxf(m, __shfl_xor(m, 4));
      m = fmaxf(m, __shfl_xor(m, 8));
#pragma unroll
      for (int cg = 0; cg < 4; ++cg)
        acc[rg][cg][qq] = exp2fast(acc[rg][cg][qq] - m);
      float s = acc[rg][0][qq] + acc[rg][1][qq] + acc[rg][2][qq] + acc[rg][3][qq];
      s += __shfl_xor(s, 1);
      s += __shfl_xor(s, 2);
      s += __shfl_xor(s, 4);
      s += __shfl_xor(s, 8);
      if (lr == 0) psq_s[w * 64 + rg * 16 + lk * 4 + qq] = s;  // own-wave segment
    }

  // W_n = max(sw,1e-8)/s_n  (row t of this block; same-wave LDS segment)
  {
    float sv = psq_s[t];
    float muw = fmaxf(sw[(size_t)b * N_ + n0 + t], 1e-8f);
    W_l[t] = muw / sv;
  }

  // iter-1 column partials: T_k = sum_n E_nk * W_n over this block's 256 rows
  float Wv[4][4];
#pragma unroll
  for (int rg = 0; rg < 4; ++rg)
#pragma unroll
    for (int qq = 0; qq < 4; ++qq)
      Wv[rg][qq] = W_l[w * 64 + rg * 16 + lk * 4 + qq];
#pragma unroll
  for (int cg = 0; cg < 4; ++cg) {
    float Tt = 0.f;
#pragma unroll
    for (int rg = 0; rg < 4; ++rg)
#pragma unroll
      for (int qq = 0; qq < 4; ++qq)
        Tt = fmaf(acc[rg][cg][qq], Wv[rg][qq], Tt);
    Tt += __shfl_xor(Tt, 16);
    Tt += __shfl_xor(Tt, 32);
    if (lk == 0) wm_l[w][cg * 16 + lr] = Tt;
  }

  // transpose-stage E (fp16) into LDS scratch (rows padded to 72 halves)
  _Float16* scr = (_Float16*)Bl + (size_t)w * 64 * 72;
#pragma unroll
  for (int rg = 0; rg < 4; ++rg)
#pragma unroll
    for (int cg = 0; cg < 4; ++cg)
#pragma unroll
      for (int qq = 0; qq < 4; ++qq)
        scr[(rg * 16 + lk * 4 + qq) * 72 + cg * 16 + lr] = (_Float16)acc[rg][cg][qq];
  __syncthreads();

  if (t < 64) {
    float T = wm_l[0][t] + wm_l[1][t] + wm_l[2][t] + wm_l[3][t];
    Tp[((size_t)b * 64 + blockIdx.x) * 64 + t] = T;
  }

  // coalesced flush of fp16 E tile
  _Float16* dst = E + ((size_t)b * N_ + n0 + w * 64) * 64;
#pragma unroll
  for (int f = 0; f < 8; ++f) {
    int u = f * 64 + l;
    int row = u >> 3, kq = u & 7;
    half8 v8 = *(const half8*)(scr + row * 72 + kq * 8);
    *(half8*)(dst + row * 64 + kq * 8) = v8;
  }
}

// ---------- fused iteration v2: register-resident, one E pass ----------
// 64 blocks/batch x 256 rows; thread t owns row n0+t entirely (64 fp16 in regs).
// row: s = E_row . V  -> W = muw/s ; col: butterfly transpose-reduce of E_row*W.
template <bool WRITE_W>
__global__ __launch_bounds__(256) void iter2_kernel(
    const _Float16* __restrict__ E, const float* __restrict__ sw,
    const float* __restrict__ Tin, float* __restrict__ Tout,
    float* __restrict__ W)
{
  __shared__ float wT[4][64];
  __shared__ __align__(16) float V_s[64];

  const int t = threadIdx.x;
  const int w = t >> 6, l = t & 63;
  const int b = blockIdx.y, blk = blockIdx.x;
  const size_t rowg = (size_t)b * N_ + blk * 256 + t;

  // prefetch sw and the full E row (8 x dwordx4 = 64 halves)
  float muw = fmaxf(sw[rowg], 1e-8f);
  uint4 ev[8];
  const uint4* ep = (const uint4*)(E + rowg * 64);
#pragma unroll
  for (int i = 0; i < 8; ++i) ev[i] = ep[i];

  // phase A: merge previous column partials -> V
  {
    const float* ti = Tin + ((size_t)b * 64 + w * 16) * 64 + l;
    float tp = 0.f;
#pragma unroll
    for (int i = 0; i < 16; ++i) tp += ti[(size_t)i * 64];
    wT[w][l] = tp;
  }
  __syncthreads();
  if (t < 64) V_s[t] = NUW / (wT[0][t] + wT[1][t] + wT[2][t] + wT[3][t]);
  __syncthreads();

  // row pass: s = sum_k E_k * V_k   (V via broadcast b128 reads)
  const unsigned* eu = (const unsigned*)ev;
  float s = 0.f;
#pragma unroll
  for (int c = 0; c < 16; ++c) {
    float4 v4 = *(const float4*)&V_s[c * 4];
    unsigned ua = eu[c * 2], ub = eu[c * 2 + 1];
    s = fmaf(cvt_lo(ua), v4.x, s);
    s = fmaf(cvt_hi(ua), v4.y, s);
    s = fmaf(cvt_lo(ub), v4.z, s);
    s = fmaf(cvt_hi(ub), v4.w, s);
  }
  float Wv = muw / s;
  if (WRITE_W) W[rowg] = Wv;

  // col pass: cur[k] = E_k * W, then 6-step butterfly transpose-reduce:
  // after the loop, lane l holds sum over the wave's 64 rows for column l.
  float cur[64];
#pragma unroll
  for (int j = 0; j < 32; ++j) {
    unsigned u = eu[j];
    cur[2 * j]     = cvt_lo(u) * Wv;
    cur[2 * j + 1] = cvt_hi(u) * Wv;
  }
#pragma unroll
  for (int si = 0; si < 6; ++si) {
    const int sp = 32 >> si;
    const bool up = (l & sp) != 0;
#pragma unroll
    for (int i = 0; i < sp; ++i) {
      float x = up ? cur[sp + i] : cur[i];
      float y = __shfl_xor(x, sp);
      cur[i] = x + y;
    }
  }
  wT[w][l] = cur[0];
  __syncthreads();
  if (t < 64)
    Tout[((size_t)b * 64 + blk) * 64 + t] =
        wT[0][t] + wT[1][t] + wT[2][t] + wT[3][t];
}

// ---------- final column merge -> V ----------
__global__ __launch_bounds__(64) void col_merge_kernel(
    const float* __restrict__ Tin, float* __restrict__ Vf)
{
  const int b = blockIdx.x;
  const int k = threadIdx.x;
  float T = 0.f;
#pragma unroll
  for (int j = 0; j < 64; ++j) T += Tin[((size_t)b * 64 + j) * 64 + k];
  Vf[b * 64 + k] = NUW / T;
}

// ---------- finalize: P = W_n * E_nk * V_k ----------
__global__ __launch_bounds__(256) void finalize_kernel(
    const _Float16* __restrict__ E, const float* __restrict__ W,
    const float* __restrict__ Vf, float* __restrict__ out)
{
  const size_t tid = (size_t)blockIdx.x * 256 + threadIdx.x;
  const size_t e0 = tid * 8;
  const int k0 = (int)(e0 & 63);
  const size_t bn = e0 >> 6;
  const int b = (int)(bn >> 14);
  const float Wv = W[bn];
  half8 ev = *(const half8*)(E + e0);
  float4 v0 = *(const float4*)(Vf + b * 64 + k0);
  float4 v1 = *(const float4*)(Vf + b * 64 + k0 + 4);
  float4 o0, o1;
  o0.x = Wv * (float)ev[0] * v0.x;
  o0.y = Wv * (float)ev[1] * v0.y;
  o0.z = Wv * (float)ev[2] * v0.z;
  o0.w = Wv * (float)ev[3] * v0.w;
  o1.x = Wv * (float)ev[4] * v1.x;
  o1.y = Wv * (float)ev[5] * v1.y;
  o1.z = Wv * (float)ev[6] * v1.z;
  o1.w = Wv * (float)ev[7] * v1.w;
  *(float4*)(out + e0) = o0;
  *(float4*)(out + e0 + 4) = o1;
}

extern "C" void kernel_launch(void* const* d_in, const int* in_sizes, int n_in,
                              void* d_out, int out_size, void* d_ws, size_t ws_size,
                              hipStream_t stream)
{
  const float* pix  = (const float*)d_in[0];
  const float* slot = (const float*)d_in[1];
  const float* sw   = (const float*)d_in[2];
  float* out = (float*)d_out;

  char* ws = (char*)d_ws;
  float* W    = (float*)ws;                          // 2 MB
  float* Vf   = (float*)(ws + (2ull << 20));         // 8 KB
  float* ssq  = (float*)(ws + (2ull << 20) + 65536); // 8 KB
  float* TpA  = (float*)(ws + (3ull << 20));         // 512 KB
  float* TpB  = (float*)(ws + (4ull << 20));         // 512 KB
  unsigned short* bhi = (unsigned short*)(ws + (5ull << 20));  // 1 MB
  unsigned short* blo = (unsigned short*)(ws + (6ull << 20));  // 1 MB
  _Float16* E = (_Float16*)(ws + (8ull << 20));      // 67 MB

  slot_prep_kernel<<<B_ * K_, 64, 0, stream>>>(slot, bhi, blo, ssq);
  logk_mfma_kernel<<<dim3(N_ / 256, B_), 256, 0, stream>>>(
      pix, bhi, blo, ssq, sw, E, TpA);

  float *im = TpA, *om = TpB;
  for (int it = 2; it <= NUM_ITERS_; ++it) {
    if (it < NUM_ITERS_)
      iter2_kernel<false><<<dim3(64, B_), 256, 0, stream>>>(E, sw, im, om, W);
    else
      iter2_kernel<true><<<dim3(64, B_), 256, 0, stream>>>(E, sw, im, om, W);
    float* tmp = im; im = om; om = tmp;
  }
  col_merge_kernel<<<B_, 64, 0, stream>>>(im, Vf);
  finalize_kernel<<<(unsigned)(((size_t)B_ * N_ * K_ / 8) / 256), 256, 0, stream>>>(
      E, W, Vf, out);
}